// Round 14
// baseline (335.008 us; speedup 1.0000x reference)
//
#include <hip/hip_runtime.h>
#include <hip/hip_bf16.h>

#define H 128
#define D_IN 256
#define NGRAPH 8

typedef __attribute__((ext_vector_type(8))) short bf16x8;
typedef __attribute__((ext_vector_type(4))) float f32x4;
typedef __attribute__((ext_vector_type(4))) int i32x4;

// ---- order-preserving float<->unsigned encoding for max-reduction
__device__ __forceinline__ unsigned fenc(float f) {
  unsigned u = __float_as_uint(f);
  return (u & 0x80000000u) ? ~u : (u | 0x80000000u);
}
__device__ __forceinline__ float fdec(unsigned e) {
  unsigned v = (e & 0x80000000u) ? (e & 0x7FFFFFFFu) : ~e;
  return __uint_as_float(v);
}
__device__ __forceinline__ unsigned short f2bf(float f) {  // RNE f32->bf16
  unsigned u = __float_as_uint(f);
  unsigned r = u + 0x7FFFu + ((u >> 16) & 1u);
  return (unsigned short)(r >> 16);
}

__global__ void init_kernel(int* __restrict__ offsets, int n1) {
  int i = blockIdx.x * blockDim.x + threadIdx.x;
  if (i < n1) offsets[i] = 0;
}

__global__ void count_kernel(const int* __restrict__ dst, int* __restrict__ offsets, int E) {
  int i = blockIdx.x * blockDim.x + threadIdx.x;
  int stride = gridDim.x * blockDim.x;
  for (int e = i; e < E; e += stride) atomicAdd(&offsets[dst[e]], 1);
}

// ---- hierarchical scan
__global__ void __launch_bounds__(1024)
scan_local(int* __restrict__ data, int* __restrict__ bsum, int n) {
  __shared__ int s[1024];
  int tid = threadIdx.x;
  int i = blockIdx.x * 1024 + tid;
  int v = (i < n) ? data[i] : 0;
  s[tid] = v;
  __syncthreads();
  for (int off = 1; off < 1024; off <<= 1) {
    int t = (tid >= off) ? s[tid - off] : 0;
    __syncthreads();
    s[tid] += t;
    __syncthreads();
  }
  if (i < n) data[i] = s[tid] - v;  // exclusive
  if (tid == 1023) bsum[blockIdx.x] = s[1023];
}

__global__ void __launch_bounds__(128)
scan_bsum(int* __restrict__ bsum, int nb) {
  __shared__ int s[128];
  int tid = threadIdx.x;
  int v = (tid < nb) ? bsum[tid] : 0;
  s[tid] = v;
  __syncthreads();
  for (int off = 1; off < 128; off <<= 1) {
    int t = (tid >= off) ? s[tid - off] : 0;
    __syncthreads();
    s[tid] += t;
    __syncthreads();
  }
  if (tid < nb) bsum[tid] = s[tid] - v;  // exclusive
}

__global__ void __launch_bounds__(1024)
scan_add(int* __restrict__ data, const int* __restrict__ bsum, int* __restrict__ cursor,
         int n, int ncur) {
  int i = blockIdx.x * 1024 + threadIdx.x;
  if (i < n) {
    int v = data[i] + bsum[blockIdx.x];
    data[i] = v;
    if (i < ncur) cursor[i] = v;
  }
}

__global__ void fill_kernel(const int* __restrict__ src, const int* __restrict__ dst,
                            int* __restrict__ cursor, int* __restrict__ esrc, int E) {
  int i = blockIdx.x * blockDim.x + threadIdx.x;
  int stride = gridDim.x * blockDim.x;
  for (int e = i; e < E; e += stride) {
    int d = dst[e];
    int p = atomicAdd(&cursor[d], 1);
    esrc[p] = src[e];
  }
}

// Pack weights to bf16 in FRAGMENT order: Bpack[s][c][g][j] = w[s*32+g*8+j][c]
__global__ void prep_weights(const float* __restrict__ wf, const float* __restrict__ wcv,
                             unsigned short* __restrict__ Bf, unsigned short* __restrict__ Bc) {
  int i = blockIdx.x * 256 + threadIdx.x;  // 65536 total
  if (i < 32768) {                          // first layer: K=256, 8 k-steps
    int s = i >> 12, r = i & 4095;
    int c = r >> 5, r2 = r & 31;
    int g = r2 >> 3, j = r2 & 7;
    int k = s * 32 + g * 8 + j;
    Bf[i] = f2bf(wf[k * H + c]);
  } else {                                  // conv layers: K=128, 4 k-steps each
    int i2 = i - 32768;
    int l = i2 >> 14, r = i2 & 16383;
    int s = r >> 12, rr = r & 4095;
    int c = rr >> 5, r2 = rr & 31;
    int g = r2 >> 3, j = r2 & 7;
    int k = s * 32 + g * 8 + j;
    Bc[i2] = f2bf(wcv[l * H * H + k * H + c]);
  }
}

// Fused GEMM [N x K] @ [K x 128] + bias + BN(eval) + ReLU -> h (bf16),
// plus linear head -> node_pred and per-graph segment-max partials -> slot.
// Round-14: OCCUPANCY lever. K chunked at BK=128 so the LDS stage buffer is
// 16 KB regardless of K (K=256 restages; 2 extra barriers) -> ~17 KB/block ->
// 9 blocks/CU by LDS; __launch_bounds__(256,8) requests 8 blocks/CU
// (VGPR cap 64 >= measured 52). Rest identical to round 13.
template <int K, bool AF32, bool FIRST>
__global__ void __launch_bounds__(256, 8)
gemm_kernel(const void* __restrict__ Ain, const unsigned short* __restrict__ Bpack,
            const float* __restrict__ bias, const float* __restrict__ bn,
            const float* __restrict__ wlin, const float* __restrict__ blin, int lidx,
            const int* __restrict__ batch, unsigned short* __restrict__ hout,
            float* __restrict__ node_pred, unsigned* __restrict__ slot, int N) {
  constexpr int BK = 128;              // staged K-chunk (bf16 cols)
  constexpr int RB = BK * 2;           // 256 B per row in LDS
  constexpr int NCHUNK = K / BK;
  __shared__ char s_a[64 * RB];        // 16 KB A chunk, swizzled; reused as h-store tile
  __shared__ float s_head[64][2];      // per-row linear-head partials (wc halves)
  __shared__ unsigned s_wsi[NGRAPH];
  const int tid = threadIdx.x;
  const int wid = tid >> 6, lane = tid & 63;
  const int wr = wid >> 1, wc = wid & 1;
  const int g = lane >> 4, l15 = lane & 15;
  const int row0blk = blockIdx.x * 64;
  if (tid < NGRAPH) s_wsi[tid] = 0u;

  f32x4 acc[2][4] = {};
  const int lrow0 = wr * 32;

  for (int ch = 0; ch < NCHUNK; ++ch) {
    // ---- stage A chunk [64 rows][128 bf16 cols], coalesced, swizzled
    if (AF32) {
      const float* A = (const float*)Ain;
#pragma unroll
      for (int it = 0; it < 8; ++it) {
        int flat = (it * 256 + tid) * 4;      // f32 index in 64x128 chunk
        int lr = flat >> 7;
        int col = flat & 127;
        int grow = row0blk + lr;
        grow = (grow < N) ? grow : (N - 1);
        float4 u = *(const float4*)(A + (size_t)grow * K + ch * BK + col);
        union { unsigned short hh[4]; uint2 d; } pk;
        pk.hh[0] = f2bf(u.x); pk.hh[1] = f2bf(u.y);
        pk.hh[2] = f2bf(u.z); pk.hh[3] = f2bf(u.w);
        int addr = lr * RB + col * 2;
        *(uint2*)(s_a + (addr ^ ((lr & 7) << 4))) = pk.d;
      }
    } else {
      const char* A = (const char*)Ain;
#pragma unroll
      for (int it = 0; it < 4; ++it) {
        int unit = it * 256 + tid;            // 16-B unit in 64x256B chunk
        int lr = unit >> 4;
        int cb = (unit & 15) * 16;
        int grow = row0blk + lr;
        grow = (grow < N) ? grow : (N - 1);
        i32x4 q = *(const i32x4*)(A + (size_t)grow * (K * 2) + ch * RB + cb);
        int addr = lr * RB + cb;
        *(i32x4*)(s_a + (addr ^ ((lr & 7) << 4))) = q;
      }
    }
    __syncthreads();

    // ---- 4 k-steps on this chunk (LDS A + coalesced packed-B loads)
#pragma unroll
    for (int s = 0; s < 4; ++s) {
      int sg = ch * 4 + s;                    // global k-step for Bpack
      bf16x8 bfr[4];
#pragma unroll
      for (int n = 0; n < 4; ++n) {
        int c = wc * 64 + n * 16 + l15;
        bfr[n] = *(const bf16x8*)(Bpack + sg * 4096 + c * 32 + g * 8);
      }
      bf16x8 af[2];
#pragma unroll
      for (int m = 0; m < 2; ++m) {
        int lr = lrow0 + m * 16 + l15;
        int addr = lr * RB + s * 64 + g * 16;
        af[m] = *(const bf16x8*)(s_a + (addr ^ ((lr & 7) << 4)));
      }
#pragma unroll
      for (int m = 0; m < 2; ++m)
#pragma unroll
        for (int n = 0; n < 4; ++n)
          acc[m][n] = __builtin_amdgcn_mfma_f32_16x16x32_bf16(af[m], bfr[n], acc[m][n], 0, 0, 0);
    }
    __syncthreads();  // before restage / epilogue LDS reuse
  }

  // ---- epilogue: bias+BN+ReLU folded to hv = acc*sc + sh
  float sc[4], sh[4], wl[4];
#pragma unroll
  for (int n = 0; n < 4; ++n) {
    int c = wc * 64 + n * 16 + l15;
    float gam = bn[c], bet = bn[H + c], mu = bn[2 * H + c], va = bn[3 * H + c];
    float rs = rsqrtf(va + 1e-5f);
    sc[n] = gam * rs;
    sh[n] = (bias[c] - mu) * gam * rs + bet;
    wl[n] = wlin[c];
  }

  char* aw = s_a + wid * 2048;  // per-wave 16x64 bf16 tile region
#pragma unroll
  for (int m = 0; m < 2; ++m) {
    float pj[4] = {0.f, 0.f, 0.f, 0.f};
#pragma unroll
    for (int n = 0; n < 4; ++n)
#pragma unroll
      for (int j = 0; j < 4; ++j) {
        float hv = fmaxf(acc[m][n][j] * sc[n] + sh[n], 0.f);
        pj[j] += hv * wl[n];
        *(unsigned short*)(aw + (g * 4 + j) * 128 + (n * 16 + l15) * 2) = f2bf(hv);
      }
    // head partial: reduce across the 16 lanes (l15) of this g-group
#pragma unroll
    for (int j = 0; j < 4; ++j) {
      pj[j] += __shfl_xor(pj[j], 1);
      pj[j] += __shfl_xor(pj[j], 2);
      pj[j] += __shfl_xor(pj[j], 4);
      pj[j] += __shfl_xor(pj[j], 8);
    }
    if (l15 == 0) {
#pragma unroll
      for (int j = 0; j < 4; ++j)
        s_head[wr * 32 + m * 16 + g * 4 + j][wc] = pj[j];
    }
    // coalesced bf16 h store (wave-private LDS bounce; DS in-order, no barrier)
    int grb = row0blk + wr * 32 + m * 16;
#pragma unroll
    for (int it = 0; it < 2; ++it) {
      int bo = lane * 16 + it * 1024;
      int r16 = bo >> 7, inrow = bo & 127;
      if (grb + r16 < N)
        *(i32x4*)((char*)hout + (size_t)(grb + r16) * 256 + wc * 128 + inrow) =
            *(i32x4*)(aw + bo);
    }
  }
  __syncthreads();
  // finish head: one thread per block-row; per-graph max into LDS only
  if (tid < 64) {
    int grh = row0blk + tid;
    if (grh < N) {
      float np = s_head[tid][0] + s_head[tid][1] + blin[lidx];
      if (FIRST) node_pred[grh] = np; else node_pred[grh] += np;
      atomicMax(&s_wsi[batch[grh]], fenc(np));
    }
  }
  __syncthreads();
  // per-block slot store: PLAIN coalesced write, zero global contention
  if (tid < NGRAPH) slot[blockIdx.x * NGRAPH + tid] = s_wsi[tid];
}

// tmp[i] = h[i] + sum_{j in-edges} h[src_j]   (bf16 storage, f32 accumulate)
__global__ void __launch_bounds__(256)
agg_kernel(const unsigned short* __restrict__ h, const int* __restrict__ offsets,
           const int* __restrict__ esrc, unsigned short* __restrict__ tmp, int n) {
  int node = blockIdx.x * 4 + (threadIdx.x >> 6);
  if (node >= n) return;
  int lane = threadIdx.x & 63;  // 2 features per lane
  const unsigned* hw = (const unsigned*)h;
  size_t base = (size_t)node * (H / 2) + lane;
  unsigned u = hw[base];
  float a0 = __uint_as_float((u & 0xFFFFu) << 16);
  float a1 = __uint_as_float(u & 0xFFFF0000u);
  int s = offsets[node], e = offsets[node + 1];
  int j = s;
  for (; j + 4 <= e; j += 4) {
    int i0 = esrc[j], i1 = esrc[j + 1], i2 = esrc[j + 2], i3 = esrc[j + 3];
    unsigned v0 = hw[(size_t)i0 * (H / 2) + lane];
    unsigned v1 = hw[(size_t)i1 * (H / 2) + lane];
    unsigned v2 = hw[(size_t)i2 * (H / 2) + lane];
    unsigned v3 = hw[(size_t)i3 * (H / 2) + lane];
    a0 += __uint_as_float((v0 & 0xFFFFu) << 16) + __uint_as_float((v1 & 0xFFFFu) << 16) +
          __uint_as_float((v2 & 0xFFFFu) << 16) + __uint_as_float((v3 & 0xFFFFu) << 16);
    a1 += __uint_as_float(v0 & 0xFFFF0000u) + __uint_as_float(v1 & 0xFFFF0000u) +
          __uint_as_float(v2 & 0xFFFF0000u) + __uint_as_float(v3 & 0xFFFF0000u);
  }
  for (; j < e; ++j) {
    unsigned v2 = hw[(size_t)esrc[j] * (H / 2) + lane];
    a0 += __uint_as_float((v2 & 0xFFFFu) << 16);
    a1 += __uint_as_float(v2 & 0xFFFF0000u);
  }
  unsigned r = ((unsigned)f2bf(a1) << 16) | (unsigned)f2bf(a0);
  ((unsigned*)tmp)[base] = r;
}

// out[g] = sum_l max_b slots[l][b][g]; 192 threads = 24 (l,g) pairs x 8 lanes
__global__ void __launch_bounds__(256)
finalize_kernel(const unsigned* __restrict__ slots, float* __restrict__ out, int nb) {
  __shared__ float red[3][NGRAPH];
  int tid = threadIdx.x;
  if (tid < 192) {
    int pair = tid >> 3, w = tid & 7;
    int l = pair >> 3, g = pair & 7;
    unsigned m = 0u;
    const unsigned* base = slots + (size_t)l * nb * NGRAPH + g;
    for (int b = w; b < nb; b += 8) m = max(m, base[b * NGRAPH]);
    m = max(m, (unsigned)__shfl_xor((int)m, 1));
    m = max(m, (unsigned)__shfl_xor((int)m, 2));
    m = max(m, (unsigned)__shfl_xor((int)m, 4));
    if (w == 0) red[l][g] = fdec(m);
  }
  __syncthreads();
  if (tid < NGRAPH) out[tid] = red[0][tid] + red[1][tid] + red[2][tid];
}

extern "C" void kernel_launch(void* const* d_in, const int* in_sizes, int n_in,
                              void* d_out, int out_size, void* d_ws, size_t ws_size,
                              hipStream_t stream) {
  const float* x        = (const float*)d_in[0];
  const int*   ei       = (const int*)d_in[1];
  const int*   batch    = (const int*)d_in[2];
  const float* w_first  = (const float*)d_in[3];
  const float* b_first  = (const float*)d_in[4];
  const float* bn_first = (const float*)d_in[5];
  const float* w_conv   = (const float*)d_in[6];
  const float* b_conv   = (const float*)d_in[7];
  const float* bn_conv  = (const float*)d_in[8];
  const float* w_lin    = (const float*)d_in[9];
  const float* b_lin    = (const float*)d_in[10];
  float* out = (float*)d_out;

  const int N = in_sizes[0] / D_IN;
  const int E = in_sizes[1] / 2;
  const int* src = ei;
  const int* dst = ei + E;

  const int gemm_grid = (N + 63) / 64;

  char* ws = (char*)d_ws;
  unsigned short* h   = (unsigned short*)ws;            // N*H bf16
  unsigned short* tmp = h + (size_t)N * H;              // N*H bf16
  unsigned short* wTf = tmp + (size_t)N * H;            // 32768 bf16 (packed w_first)
  unsigned short* wTc = wTf + H * D_IN;                 // 32768 bf16 (packed w_conv x2)
  int* offsets = (int*)(wTc + 2 * H * H);
  int* cursor  = offsets + (N + 1);
  int* esrc    = cursor + N;
  int* bsum    = esrc + E;                              // scan block sums (<=128)
  unsigned* slots = (unsigned*)(bsum + 128);            // [3][gemm_grid][8]
  float* node_pred = out + NGRAPH;

  const int nscan = N + 1;
  const int nb = (nscan + 1023) / 1024;                 // 98 for N=100000 (must be <=128)

  init_kernel<<<(N + 256) / 256, 256, 0, stream>>>(offsets, N + 1);
  count_kernel<<<1024, 256, 0, stream>>>(dst, offsets, E);
  scan_local<<<nb, 1024, 0, stream>>>(offsets, bsum, nscan);
  scan_bsum<<<1, 128, 0, stream>>>(bsum, nb);
  scan_add<<<nb, 1024, 0, stream>>>(offsets, bsum, cursor, nscan, N);
  fill_kernel<<<1024, 256, 0, stream>>>(src, dst, cursor, esrc, E);
  prep_weights<<<256, 256, 0, stream>>>(w_first, w_conv, wTf, wTc);

  gemm_kernel<D_IN, true, true><<<gemm_grid, 256, 0, stream>>>(
      x, wTf, b_first, bn_first, w_lin, b_lin, 0, batch, h, node_pred, slots, N);
  for (int l = 0; l < 2; ++l) {
    agg_kernel<<<(N + 3) / 4, 256, 0, stream>>>(h, offsets, esrc, tmp, N);
    gemm_kernel<H, false, false><<<gemm_grid, 256, 0, stream>>>(
        tmp, wTc + (size_t)l * 16384, b_conv + (size_t)l * H, bn_conv + (size_t)l * 4 * H,
        w_lin + (size_t)(l + 1) * H, b_lin, l + 1, batch, h, node_pred,
        slots + (size_t)(l + 1) * gemm_grid * NGRAPH, N);
  }
  finalize_kernel<<<1, 256, 0, stream>>>(slots, out, gemm_grid);
}

// Round 15
// 252.422 us; speedup vs baseline: 1.3272x; 1.3272x over previous
//
#include <hip/hip_runtime.h>
#include <hip/hip_bf16.h>

#define H 128
#define D_IN 256
#define NGRAPH 8

typedef __attribute__((ext_vector_type(8))) short bf16x8;
typedef __attribute__((ext_vector_type(4))) float f32x4;
typedef __attribute__((ext_vector_type(4))) int i32x4;

// ---- order-preserving float<->unsigned encoding for max-reduction
__device__ __forceinline__ unsigned fenc(float f) {
  unsigned u = __float_as_uint(f);
  return (u & 0x80000000u) ? ~u : (u | 0x80000000u);
}
__device__ __forceinline__ float fdec(unsigned e) {
  unsigned v = (e & 0x80000000u) ? (e & 0x7FFFFFFFu) : ~e;
  return __uint_as_float(v);
}
__device__ __forceinline__ unsigned short f2bf(float f) {  // RNE f32->bf16
  unsigned u = __float_as_uint(f);
  unsigned r = u + 0x7FFFu + ((u >> 16) & 1u);
  return (unsigned short)(r >> 16);
}

__global__ void init_kernel(int* __restrict__ offsets, int n1) {
  int i = blockIdx.x * blockDim.x + threadIdx.x;
  if (i < n1) offsets[i] = 0;
}

__global__ void count_kernel(const int* __restrict__ dst, int* __restrict__ offsets, int E) {
  int i = blockIdx.x * blockDim.x + threadIdx.x;
  int stride = gridDim.x * blockDim.x;
  for (int e = i; e < E; e += stride) atomicAdd(&offsets[dst[e]], 1);
}

// ---- hierarchical scan
__global__ void __launch_bounds__(1024)
scan_local(int* __restrict__ data, int* __restrict__ bsum, int n) {
  __shared__ int s[1024];
  int tid = threadIdx.x;
  int i = blockIdx.x * 1024 + tid;
  int v = (i < n) ? data[i] : 0;
  s[tid] = v;
  __syncthreads();
  for (int off = 1; off < 1024; off <<= 1) {
    int t = (tid >= off) ? s[tid - off] : 0;
    __syncthreads();
    s[tid] += t;
    __syncthreads();
  }
  if (i < n) data[i] = s[tid] - v;  // exclusive
  if (tid == 1023) bsum[blockIdx.x] = s[1023];
}

__global__ void __launch_bounds__(128)
scan_bsum(int* __restrict__ bsum, int nb) {
  __shared__ int s[128];
  int tid = threadIdx.x;
  int v = (tid < nb) ? bsum[tid] : 0;
  s[tid] = v;
  __syncthreads();
  for (int off = 1; off < 128; off <<= 1) {
    int t = (tid >= off) ? s[tid - off] : 0;
    __syncthreads();
    s[tid] += t;
    __syncthreads();
  }
  if (tid < nb) bsum[tid] = s[tid] - v;  // exclusive
}

__global__ void __launch_bounds__(1024)
scan_add(int* __restrict__ data, const int* __restrict__ bsum, int* __restrict__ cursor,
         int n, int ncur) {
  int i = blockIdx.x * 1024 + threadIdx.x;
  if (i < n) {
    int v = data[i] + bsum[blockIdx.x];
    data[i] = v;
    if (i < ncur) cursor[i] = v;
  }
}

__global__ void fill_kernel(const int* __restrict__ src, const int* __restrict__ dst,
                            int* __restrict__ cursor, int* __restrict__ esrc, int E) {
  int i = blockIdx.x * blockDim.x + threadIdx.x;
  int stride = gridDim.x * blockDim.x;
  for (int e = i; e < E; e += stride) {
    int d = dst[e];
    int p = atomicAdd(&cursor[d], 1);
    esrc[p] = src[e];
  }
}

// Pack weights to bf16 in FRAGMENT order: Bpack[s][c][g][j] = w[s*32+g*8+j][c]
__global__ void prep_weights(const float* __restrict__ wf, const float* __restrict__ wcv,
                             unsigned short* __restrict__ Bf, unsigned short* __restrict__ Bc) {
  int i = blockIdx.x * 256 + threadIdx.x;  // 65536 total
  if (i < 32768) {                          // first layer: K=256, 8 k-steps
    int s = i >> 12, r = i & 4095;
    int c = r >> 5, r2 = r & 31;
    int g = r2 >> 3, j = r2 & 7;
    int k = s * 32 + g * 8 + j;
    Bf[i] = f2bf(wf[k * H + c]);
  } else {                                  // conv layers: K=128, 4 k-steps each
    int i2 = i - 32768;
    int l = i2 >> 14, r = i2 & 16383;
    int s = r >> 12, rr = r & 4095;
    int c = rr >> 5, r2 = rr & 31;
    int g = r2 >> 3, j = r2 & 7;
    int k = s * 32 + g * 8 + j;
    Bc[i2] = f2bf(wcv[l * H * H + k * H + c]);
  }
}

// Fused GEMM [N x K] @ [K x 128] + bias + BN(eval) + ReLU -> h (bf16),
// plus linear head -> node_pred and per-graph segment-max partials -> slot.
// Round-15: BK=128 chunking kept (17 KB LDS -> 9 blocks/CU by LDS) but
// launch_bounds relaxed to (256,4): VGPR cap 128 so the compiler keeps its
// natural ~52 regs (round-14's (256,8) forced VGPR=32 -> 200 MB/dispatch of
// scratch spill traffic, corrupting the occupancy experiment).
template <int K, bool AF32, bool FIRST>
__global__ void __launch_bounds__(256, 4)
gemm_kernel(const void* __restrict__ Ain, const unsigned short* __restrict__ Bpack,
            const float* __restrict__ bias, const float* __restrict__ bn,
            const float* __restrict__ wlin, const float* __restrict__ blin, int lidx,
            const int* __restrict__ batch, unsigned short* __restrict__ hout,
            float* __restrict__ node_pred, unsigned* __restrict__ slot, int N) {
  constexpr int BK = 128;              // staged K-chunk (bf16 cols)
  constexpr int RB = BK * 2;           // 256 B per row in LDS
  constexpr int NCHUNK = K / BK;
  __shared__ char s_a[64 * RB];        // 16 KB A chunk, swizzled; reused as h-store tile
  __shared__ float s_head[64][2];      // per-row linear-head partials (wc halves)
  __shared__ unsigned s_wsi[NGRAPH];
  const int tid = threadIdx.x;
  const int wid = tid >> 6, lane = tid & 63;
  const int wr = wid >> 1, wc = wid & 1;
  const int g = lane >> 4, l15 = lane & 15;
  const int row0blk = blockIdx.x * 64;
  if (tid < NGRAPH) s_wsi[tid] = 0u;

  f32x4 acc[2][4] = {};
  const int lrow0 = wr * 32;

  for (int ch = 0; ch < NCHUNK; ++ch) {
    // ---- stage A chunk [64 rows][128 bf16 cols], coalesced, swizzled
    if (AF32) {
      const float* A = (const float*)Ain;
#pragma unroll
      for (int it = 0; it < 8; ++it) {
        int flat = (it * 256 + tid) * 4;      // f32 index in 64x128 chunk
        int lr = flat >> 7;
        int col = flat & 127;
        int grow = row0blk + lr;
        grow = (grow < N) ? grow : (N - 1);
        float4 u = *(const float4*)(A + (size_t)grow * K + ch * BK + col);
        union { unsigned short hh[4]; uint2 d; } pk;
        pk.hh[0] = f2bf(u.x); pk.hh[1] = f2bf(u.y);
        pk.hh[2] = f2bf(u.z); pk.hh[3] = f2bf(u.w);
        int addr = lr * RB + col * 2;
        *(uint2*)(s_a + (addr ^ ((lr & 7) << 4))) = pk.d;
      }
    } else {
      const char* A = (const char*)Ain;
#pragma unroll
      for (int it = 0; it < 4; ++it) {
        int unit = it * 256 + tid;            // 16-B unit in 64x256B chunk
        int lr = unit >> 4;
        int cb = (unit & 15) * 16;
        int grow = row0blk + lr;
        grow = (grow < N) ? grow : (N - 1);
        i32x4 q = *(const i32x4*)(A + (size_t)grow * (K * 2) + ch * RB + cb);
        int addr = lr * RB + cb;
        *(i32x4*)(s_a + (addr ^ ((lr & 7) << 4))) = q;
      }
    }
    __syncthreads();

    // ---- 4 k-steps on this chunk (LDS A + coalesced packed-B loads)
#pragma unroll
    for (int s = 0; s < 4; ++s) {
      int sg = ch * 4 + s;                    // global k-step for Bpack
      bf16x8 bfr[4];
#pragma unroll
      for (int n = 0; n < 4; ++n) {
        int c = wc * 64 + n * 16 + l15;
        bfr[n] = *(const bf16x8*)(Bpack + sg * 4096 + c * 32 + g * 8);
      }
      bf16x8 af[2];
#pragma unroll
      for (int m = 0; m < 2; ++m) {
        int lr = lrow0 + m * 16 + l15;
        int addr = lr * RB + s * 64 + g * 16;
        af[m] = *(const bf16x8*)(s_a + (addr ^ ((lr & 7) << 4)));
      }
#pragma unroll
      for (int m = 0; m < 2; ++m)
#pragma unroll
        for (int n = 0; n < 4; ++n)
          acc[m][n] = __builtin_amdgcn_mfma_f32_16x16x32_bf16(af[m], bfr[n], acc[m][n], 0, 0, 0);
    }
    __syncthreads();  // before restage / epilogue LDS reuse
  }

  // ---- epilogue: bias+BN+ReLU folded to hv = acc*sc + sh
  float sc[4], sh[4], wl[4];
#pragma unroll
  for (int n = 0; n < 4; ++n) {
    int c = wc * 64 + n * 16 + l15;
    float gam = bn[c], bet = bn[H + c], mu = bn[2 * H + c], va = bn[3 * H + c];
    float rs = rsqrtf(va + 1e-5f);
    sc[n] = gam * rs;
    sh[n] = (bias[c] - mu) * gam * rs + bet;
    wl[n] = wlin[c];
  }

  char* aw = s_a + wid * 2048;  // per-wave 16x64 bf16 tile region
#pragma unroll
  for (int m = 0; m < 2; ++m) {
    float pj[4] = {0.f, 0.f, 0.f, 0.f};
#pragma unroll
    for (int n = 0; n < 4; ++n)
#pragma unroll
      for (int j = 0; j < 4; ++j) {
        float hv = fmaxf(acc[m][n][j] * sc[n] + sh[n], 0.f);
        pj[j] += hv * wl[n];
        *(unsigned short*)(aw + (g * 4 + j) * 128 + (n * 16 + l15) * 2) = f2bf(hv);
      }
    // head partial: reduce across the 16 lanes (l15) of this g-group
#pragma unroll
    for (int j = 0; j < 4; ++j) {
      pj[j] += __shfl_xor(pj[j], 1);
      pj[j] += __shfl_xor(pj[j], 2);
      pj[j] += __shfl_xor(pj[j], 4);
      pj[j] += __shfl_xor(pj[j], 8);
    }
    if (l15 == 0) {
#pragma unroll
      for (int j = 0; j < 4; ++j)
        s_head[wr * 32 + m * 16 + g * 4 + j][wc] = pj[j];
    }
    // coalesced bf16 h store (wave-private LDS bounce; DS in-order, no barrier)
    int grb = row0blk + wr * 32 + m * 16;
#pragma unroll
    for (int it = 0; it < 2; ++it) {
      int bo = lane * 16 + it * 1024;
      int r16 = bo >> 7, inrow = bo & 127;
      if (grb + r16 < N)
        *(i32x4*)((char*)hout + (size_t)(grb + r16) * 256 + wc * 128 + inrow) =
            *(i32x4*)(aw + bo);
    }
  }
  __syncthreads();
  // finish head: one thread per block-row; per-graph max into LDS only
  if (tid < 64) {
    int grh = row0blk + tid;
    if (grh < N) {
      float np = s_head[tid][0] + s_head[tid][1] + blin[lidx];
      if (FIRST) node_pred[grh] = np; else node_pred[grh] += np;
      atomicMax(&s_wsi[batch[grh]], fenc(np));
    }
  }
  __syncthreads();
  // per-block slot store: PLAIN coalesced write, zero global contention
  if (tid < NGRAPH) slot[blockIdx.x * NGRAPH + tid] = s_wsi[tid];
}

// tmp[i] = h[i] + sum_{j in-edges} h[src_j]   (bf16 storage, f32 accumulate)
__global__ void __launch_bounds__(256)
agg_kernel(const unsigned short* __restrict__ h, const int* __restrict__ offsets,
           const int* __restrict__ esrc, unsigned short* __restrict__ tmp, int n) {
  int node = blockIdx.x * 4 + (threadIdx.x >> 6);
  if (node >= n) return;
  int lane = threadIdx.x & 63;  // 2 features per lane
  const unsigned* hw = (const unsigned*)h;
  size_t base = (size_t)node * (H / 2) + lane;
  unsigned u = hw[base];
  float a0 = __uint_as_float((u & 0xFFFFu) << 16);
  float a1 = __uint_as_float(u & 0xFFFF0000u);
  int s = offsets[node], e = offsets[node + 1];
  int j = s;
  for (; j + 4 <= e; j += 4) {
    int i0 = esrc[j], i1 = esrc[j + 1], i2 = esrc[j + 2], i3 = esrc[j + 3];
    unsigned v0 = hw[(size_t)i0 * (H / 2) + lane];
    unsigned v1 = hw[(size_t)i1 * (H / 2) + lane];
    unsigned v2 = hw[(size_t)i2 * (H / 2) + lane];
    unsigned v3 = hw[(size_t)i3 * (H / 2) + lane];
    a0 += __uint_as_float((v0 & 0xFFFFu) << 16) + __uint_as_float((v1 & 0xFFFFu) << 16) +
          __uint_as_float((v2 & 0xFFFFu) << 16) + __uint_as_float((v3 & 0xFFFFu) << 16);
    a1 += __uint_as_float(v0 & 0xFFFF0000u) + __uint_as_float(v1 & 0xFFFF0000u) +
          __uint_as_float(v2 & 0xFFFF0000u) + __uint_as_float(v3 & 0xFFFF0000u);
  }
  for (; j < e; ++j) {
    unsigned v2 = hw[(size_t)esrc[j] * (H / 2) + lane];
    a0 += __uint_as_float((v2 & 0xFFFFu) << 16);
    a1 += __uint_as_float(v2 & 0xFFFF0000u);
  }
  unsigned r = ((unsigned)f2bf(a1) << 16) | (unsigned)f2bf(a0);
  ((unsigned*)tmp)[base] = r;
}

// out[g] = sum_l max_b slots[l][b][g]; 192 threads = 24 (l,g) pairs x 8 lanes
__global__ void __launch_bounds__(256)
finalize_kernel(const unsigned* __restrict__ slots, float* __restrict__ out, int nb) {
  __shared__ float red[3][NGRAPH];
  int tid = threadIdx.x;
  if (tid < 192) {
    int pair = tid >> 3, w = tid & 7;
    int l = pair >> 3, g = pair & 7;
    unsigned m = 0u;
    const unsigned* base = slots + (size_t)l * nb * NGRAPH + g;
    for (int b = w; b < nb; b += 8) m = max(m, base[b * NGRAPH]);
    m = max(m, (unsigned)__shfl_xor((int)m, 1));
    m = max(m, (unsigned)__shfl_xor((int)m, 2));
    m = max(m, (unsigned)__shfl_xor((int)m, 4));
    if (w == 0) red[l][g] = fdec(m);
  }
  __syncthreads();
  if (tid < NGRAPH) out[tid] = red[0][tid] + red[1][tid] + red[2][tid];
}

extern "C" void kernel_launch(void* const* d_in, const int* in_sizes, int n_in,
                              void* d_out, int out_size, void* d_ws, size_t ws_size,
                              hipStream_t stream) {
  const float* x        = (const float*)d_in[0];
  const int*   ei       = (const int*)d_in[1];
  const int*   batch    = (const int*)d_in[2];
  const float* w_first  = (const float*)d_in[3];
  const float* b_first  = (const float*)d_in[4];
  const float* bn_first = (const float*)d_in[5];
  const float* w_conv   = (const float*)d_in[6];
  const float* b_conv   = (const float*)d_in[7];
  const float* bn_conv  = (const float*)d_in[8];
  const float* w_lin    = (const float*)d_in[9];
  const float* b_lin    = (const float*)d_in[10];
  float* out = (float*)d_out;

  const int N = in_sizes[0] / D_IN;
  const int E = in_sizes[1] / 2;
  const int* src = ei;
  const int* dst = ei + E;

  const int gemm_grid = (N + 63) / 64;

  char* ws = (char*)d_ws;
  unsigned short* h   = (unsigned short*)ws;            // N*H bf16
  unsigned short* tmp = h + (size_t)N * H;              // N*H bf16
  unsigned short* wTf = tmp + (size_t)N * H;            // 32768 bf16 (packed w_first)
  unsigned short* wTc = wTf + H * D_IN;                 // 32768 bf16 (packed w_conv x2)
  int* offsets = (int*)(wTc + 2 * H * H);
  int* cursor  = offsets + (N + 1);
  int* esrc    = cursor + N;
  int* bsum    = esrc + E;                              // scan block sums (<=128)
  unsigned* slots = (unsigned*)(bsum + 128);            // [3][gemm_grid][8]
  float* node_pred = out + NGRAPH;

  const int nscan = N + 1;
  const int nb = (nscan + 1023) / 1024;                 // 98 for N=100000 (must be <=128)

  init_kernel<<<(N + 256) / 256, 256, 0, stream>>>(offsets, N + 1);
  count_kernel<<<1024, 256, 0, stream>>>(dst, offsets, E);
  scan_local<<<nb, 1024, 0, stream>>>(offsets, bsum, nscan);
  scan_bsum<<<1, 128, 0, stream>>>(bsum, nb);
  scan_add<<<nb, 1024, 0, stream>>>(offsets, bsum, cursor, nscan, N);
  fill_kernel<<<1024, 256, 0, stream>>>(src, dst, cursor, esrc, E);
  prep_weights<<<256, 256, 0, stream>>>(w_first, w_conv, wTf, wTc);

  gemm_kernel<D_IN, true, true><<<gemm_grid, 256, 0, stream>>>(
      x, wTf, b_first, bn_first, w_lin, b_lin, 0, batch, h, node_pred, slots, N);
  for (int l = 0; l < 2; ++l) {
    agg_kernel<<<(N + 3) / 4, 256, 0, stream>>>(h, offsets, esrc, tmp, N);
    gemm_kernel<H, false, false><<<gemm_grid, 256, 0, stream>>>(
        tmp, wTc + (size_t)l * 16384, b_conv + (size_t)l * H, bn_conv + (size_t)l * 4 * H,
        w_lin + (size_t)(l + 1) * H, b_lin, l + 1, batch, h, node_pred,
        slots + (size_t)(l + 1) * gemm_grid * NGRAPH, N);
  }
  finalize_kernel<<<1, 256, 0, stream>>>(slots, out, gemm_grid);
}